// Round 4
// baseline (696.188 us; speedup 1.0000x reference)
//
#include <hip/hip_runtime.h>
#include <math.h>

#define D_MODEL 1024
#define D_HIDDEN 4096
#define NEXP 8
#define NTOK 8192
#define CAP 1280

#define BM 128
#define BN 128
#define BK2 64  // K-slab per barrier pair: 32 MFMAs between barriers, 32 KB LDS

typedef __attribute__((ext_vector_type(8))) short short8x;
typedef __attribute__((ext_vector_type(4))) short short4x;
typedef __attribute__((ext_vector_type(4))) float float4x;

__device__ __forceinline__ short f2bf(float f) {
  unsigned u = __float_as_uint(f);
  unsigned r = (u + 0x7FFFu + ((u >> 16) & 1u)) >> 16;  // RNE
  return (short)r;
}
__device__ __forceinline__ float bf2f(short s) {
  return __uint_as_float(((unsigned)(unsigned short)s) << 16);
}
// tanh-GELU = v * sigmoid(v*(1.5957691216 + 0.0713548163*v^2)); err ~5e-4 abs,
// far under bf16-scale threshold (headroom 0.018). ~8 VALU ops vs ~30+ for erff.
__device__ __forceinline__ float gelu_fast(float v) {
  float u2 = v * (1.5957691216f + 0.0713548163f * v * v);
  return v / (1.0f + __expf(-u2));
}

#define GLDS16(g, l)                                                        \
  __builtin_amdgcn_global_load_lds(                                         \
      (const __attribute__((address_space(1))) void*)(g),                   \
      (__attribute__((address_space(3))) void*)(l), 16, 0, 0)

// ---------------- convert x: fp32 -> bf16, same layout ----------------
__global__ __launch_bounds__(256) void convert_x_kernel(
    const float* __restrict__ x, short* __restrict__ xbf) {
  size_t i = ((size_t)blockIdx.x * 256 + threadIdx.x) * 8;
  const float4* s = (const float4*)(x + i);
  float4 a = s[0], b = s[1];
  short8x o;
  o[0] = f2bf(a.x); o[1] = f2bf(a.y); o[2] = f2bf(a.z); o[3] = f2bf(a.w);
  o[4] = f2bf(b.x); o[5] = f2bf(b.y); o[6] = f2bf(b.z); o[7] = f2bf(b.w);
  *(short8x*)(xbf + i) = o;
}

// ------- transpose+convert: in [E][K][N] fp32 -> out [E][N][K] bf16 -------
__global__ __launch_bounds__(256) void transpose_kernel(
    const float* __restrict__ in, short* __restrict__ out, int K, int N) {
  __shared__ short tile[64][65];
  int n0 = blockIdx.x * 64, k0 = blockIdx.y * 64, e = blockIdx.z;
  int tid = threadIdx.x;
  int cr = tid >> 4;
  int cc = (tid & 15) * 4;
  const float* src = in + (size_t)e * K * N;
#pragma unroll
  for (int p = 0; p < 4; ++p) {
    int r = p * 16 + cr;
    float4 v = *(const float4*)(src + (size_t)(k0 + r) * N + n0 + cc);
    tile[r][cc] = f2bf(v.x); tile[r][cc + 1] = f2bf(v.y);
    tile[r][cc + 2] = f2bf(v.z); tile[r][cc + 3] = f2bf(v.w);
  }
  __syncthreads();
  short* dst = out + (size_t)e * N * K;
#pragma unroll
  for (int p = 0; p < 4; ++p) {
    int nr = p * 16 + cr;
    short4x s;
#pragma unroll
    for (int j = 0; j < 4; ++j) s[j] = tile[cc + j][nr];
    *(short4x*)(dst + (size_t)(n0 + nr) * K + k0 + cc) = s;
  }
}

// ---------------- Router ----------------
__global__ __launch_bounds__(256) void router_kernel(
    const float* __restrict__ x, const float* __restrict__ rw,
    const float* __restrict__ rb, int2* __restrict__ tok_experts,
    float2* __restrict__ tok_gates) {
  int t = blockIdx.x * 4 + (threadIdx.x >> 6);
  int lane = threadIdx.x & 63;
  const float* xr = x + (size_t)t * D_MODEL;
  float acc[8];
#pragma unroll
  for (int e = 0; e < 8; ++e) acc[e] = 0.f;
#pragma unroll
  for (int kk = 0; kk < 16; ++kk) {
    int k = kk * 64 + lane;
    float xv = xr[k];
    const float4* wr = (const float4*)(rw + (size_t)k * 8);
    float4 w0 = wr[0], w1v = wr[1];
    acc[0] += xv * w0.x;  acc[1] += xv * w0.y;
    acc[2] += xv * w0.z;  acc[3] += xv * w0.w;
    acc[4] += xv * w1v.x; acc[5] += xv * w1v.y;
    acc[6] += xv * w1v.z; acc[7] += xv * w1v.w;
  }
#pragma unroll
  for (int off = 32; off > 0; off >>= 1) {
#pragma unroll
    for (int e = 0; e < 8; ++e) acc[e] += __shfl_xor(acc[e], off, 64);
  }
  if (lane == 0) {
    float lg[8];
#pragma unroll
    for (int e = 0; e < 8; ++e) lg[e] = acc[e] + rb[e];
    int e0 = 0;
#pragma unroll
    for (int e = 1; e < 8; ++e) if (lg[e] > lg[e0]) e0 = e;
    int e1 = (e0 == 0) ? 1 : 0;
#pragma unroll
    for (int e = 0; e < 8; ++e) if (e != e0 && lg[e] > lg[e1]) e1 = e;
    float mx = lg[e0];
    float s = 0.f;
#pragma unroll
    for (int e = 0; e < 8; ++e) s += expf(lg[e] - mx);
    float inv = 1.f / s;
    tok_experts[t] = make_int2(e0, e1);
    tok_gates[t] = make_float2(expf(lg[e0] - mx) * inv, expf(lg[e1] - mx) * inv);
  }
}

// ---------------- Scan ----------------
__global__ __launch_bounds__(1024) void scan_kernel(
    const int2* __restrict__ tok_experts, int* __restrict__ slot_token,
    int* __restrict__ token_rows) {
  int e = blockIdx.x;
  int tid = threadIdx.x;
  for (int i = tid; i < CAP; i += 1024) slot_token[e * CAP + i] = -1;
  __shared__ int wsum[16];
  __shared__ int running;
  if (tid == 0) running = 0;
  __syncthreads();
  int lane = tid & 63, wid = tid >> 6;
  unsigned long long lmask = (1ull << lane) - 1ull;
  for (int base = 0; base < NTOK; base += 1024) {
    int t = base + tid;
    int2 ee = tok_experts[t];
    int m = (ee.x == e || ee.y == e) ? 1 : 0;
    unsigned long long bal = __ballot(m);
    int prefix = __popcll(bal & lmask);
    if (lane == 0) wsum[wid] = (int)__popcll(bal);
    __syncthreads();
    if (tid == 0) {
      int s = running;
#pragma unroll
      for (int w = 0; w < 16; ++w) { int v = wsum[w]; wsum[w] = s; s += v; }
      running = s;
    }
    __syncthreads();
    if (m) {
      int pos = wsum[wid] + prefix;
      int which = (ee.x == e) ? 0 : 1;
      if (pos < CAP) {
        slot_token[e * CAP + pos] = t;
        token_rows[2 * t + which] = e * CAP + pos;
      } else {
        token_rows[2 * t + which] = -1;
      }
    }
    __syncthreads();
  }
}

// LDS tile: 128 rows x 128 B (BK2=64 bf16), unpadded; 16B-chunk c of row r at
// slot (c + ((r>>1)&7)) & 7. Staging = HW lane*16 (conflict-free); fragment
// ds_read_b128: uniform 8 lanes/slot-class, 2/class per quarter-phase (free).

// ---------------- GEMM1: h = gelu(gather(xbf) @ w1t[e]^T + b1[e]) ------------
__global__ __launch_bounds__(256) void gemm1_fast(
    const short* __restrict__ xbf, const short* __restrict__ w1t,
    const float* __restrict__ b1, const int* __restrict__ slot_token,
    short* __restrict__ h) {
  __shared__ short As[BM * BK2];  // 16 KB
  __shared__ short Bs[BN * BK2];  // 16 KB
  __shared__ int rowtok[BM];
  int e = blockIdx.z, rt = blockIdx.y, ct = blockIdx.x;
  int tid = threadIdx.x;
  if (tid < BM) {
    int t = slot_token[e * CAP + rt * BM + tid];
    rowtok[tid] = t < 0 ? 0 : t;  // dropped slots: garbage rows, never gathered
  }
  __syncthreads();
  int lane = tid & 63, w = tid >> 6;

  // staging: pass p covers rows p*32 + srow, srow = w*8 + (lane>>3)
  int srow = w * 8 + (lane >> 3);
  int slot = lane & 7;
  int cA = (slot - ((srow >> 1) & 7)) & 7;  // gmem chunk; same for all passes
  const char* agm[4];
  char* alds[4];
  char* blds[4];
#pragma unroll
  for (int p = 0; p < 4; ++p) {
    int r = p * 32 + srow;
    agm[p] = (const char*)(xbf + (size_t)rowtok[r] * D_MODEL) + cA * 16;
    alds[p] = (char*)As + (r * 8 + slot) * 16;
    blds[p] = (char*)Bs + (r * 8 + slot) * 16;
  }
  const char* bgm0 =
      (const char*)(w1t + ((size_t)e * D_HIDDEN + ct * BN + srow) * D_MODEL) + cA * 16;
  const size_t bstride = (size_t)32 * D_MODEL * 2;

  int l15 = lane & 15, q = lane >> 4;
  const char* A0 = (const char*)As + (w * 32 + l15) * 128;
  const char* B0 = (const char*)Bs + l15 * 128;
  int sw0 = (((q + (l15 >> 1)) & 7)) * 16;
  int sw1 = (((4 + q + (l15 >> 1)) & 7)) * 16;

  float4x acc[2][8];
#pragma unroll
  for (int i = 0; i < 2; ++i)
#pragma unroll
    for (int j = 0; j < 8; ++j) acc[i][j] = (float4x){0.f, 0.f, 0.f, 0.f};

  for (int k0 = 0; k0 < D_MODEL; k0 += BK2) {
    __syncthreads();
    int kb = k0 * 2;
#pragma unroll
    for (int p = 0; p < 4; ++p) GLDS16(agm[p] + kb, alds[p]);
#pragma unroll
    for (int p = 0; p < 4; ++p) GLDS16(bgm0 + p * bstride + kb, blds[p]);
    __syncthreads();
    short8x a00 = *(const short8x*)(A0 + sw0);
    short8x a10 = *(const short8x*)(A0 + 2048 + sw0);
    short8x a01 = *(const short8x*)(A0 + sw1);
    short8x a11 = *(const short8x*)(A0 + 2048 + sw1);
#pragma unroll
    for (int j = 0; j < 8; ++j) {
      short8x b0 = *(const short8x*)(B0 + j * 2048 + sw0);
      acc[0][j] = __builtin_amdgcn_mfma_f32_16x16x32_bf16(a00, b0, acc[0][j], 0, 0, 0);
      acc[1][j] = __builtin_amdgcn_mfma_f32_16x16x32_bf16(a10, b0, acc[1][j], 0, 0, 0);
      short8x b1v = *(const short8x*)(B0 + j * 2048 + sw1);
      acc[0][j] = __builtin_amdgcn_mfma_f32_16x16x32_bf16(a01, b1v, acc[0][j], 0, 0, 0);
      acc[1][j] = __builtin_amdgcn_mfma_f32_16x16x32_bf16(a11, b1v, acc[1][j], 0, 0, 0);
    }
  }
  int col0 = ct * BN;
  int rbase = q * 4;
#pragma unroll
  for (int i = 0; i < 2; ++i) {
#pragma unroll
    for (int j = 0; j < 8; ++j) {
      int col = col0 + j * 16 + l15;
      float bias = b1[e * D_HIDDEN + col];
#pragma unroll
      for (int r = 0; r < 4; ++r) {
        int grow = rt * BM + w * 32 + i * 16 + rbase + r;
        float v = gelu_fast(acc[i][j][r] + bias);
        h[(size_t)(e * CAP + grow) * D_HIDDEN + col] = f2bf(v);
      }
    }
  }
}

// ---------------- GEMM2: out2 = h @ w2t[e]^T + b2[e] -------------------------
__global__ __launch_bounds__(256) void gemm2_fast(
    const short* __restrict__ h, const short* __restrict__ w2t,
    const float* __restrict__ b2, short* __restrict__ out2) {
  __shared__ short As[BM * BK2];
  __shared__ short Bs[BN * BK2];
  int e = blockIdx.z, rt = blockIdx.y, ct = blockIdx.x;
  int tid = threadIdx.x;
  int lane = tid & 63, w = tid >> 6;

  int srow = w * 8 + (lane >> 3);
  int slot = lane & 7;
  int cA = (slot - ((srow >> 1) & 7)) & 7;
  char* alds[4];
  char* blds[4];
#pragma unroll
  for (int p = 0; p < 4; ++p) {
    int r = p * 32 + srow;
    alds[p] = (char*)As + (r * 8 + slot) * 16;
    blds[p] = (char*)Bs + (r * 8 + slot) * 16;
  }
  const char* agm0 =
      (const char*)(h + (size_t)(e * CAP + rt * BM + srow) * D_HIDDEN) + cA * 16;
  const char* bgm0 =
      (const char*)(w2t + ((size_t)e * D_MODEL + ct * BN + srow) * D_HIDDEN) + cA * 16;
  const size_t astride = (size_t)32 * D_HIDDEN * 2;

  int l15 = lane & 15, q = lane >> 4;
  const char* A0 = (const char*)As + (w * 32 + l15) * 128;
  const char* B0 = (const char*)Bs + l15 * 128;
  int sw0 = (((q + (l15 >> 1)) & 7)) * 16;
  int sw1 = (((4 + q + (l15 >> 1)) & 7)) * 16;

  float4x acc[2][8];
#pragma unroll
  for (int i = 0; i < 2; ++i)
#pragma unroll
    for (int j = 0; j < 8; ++j) acc[i][j] = (float4x){0.f, 0.f, 0.f, 0.f};

  for (int k0 = 0; k0 < D_HIDDEN; k0 += BK2) {
    __syncthreads();
    int kb = k0 * 2;
#pragma unroll
    for (int p = 0; p < 4; ++p) GLDS16(agm0 + p * astride + kb, alds[p]);
#pragma unroll
    for (int p = 0; p < 4; ++p) GLDS16(bgm0 + p * astride + kb, blds[p]);
    __syncthreads();
    short8x a00 = *(const short8x*)(A0 + sw0);
    short8x a10 = *(const short8x*)(A0 + 2048 + sw0);
    short8x a01 = *(const short8x*)(A0 + sw1);
    short8x a11 = *(const short8x*)(A0 + 2048 + sw1);
#pragma unroll
    for (int j = 0; j < 8; ++j) {
      short8x b0 = *(const short8x*)(B0 + j * 2048 + sw0);
      acc[0][j] = __builtin_amdgcn_mfma_f32_16x16x32_bf16(a00, b0, acc[0][j], 0, 0, 0);
      acc[1][j] = __builtin_amdgcn_mfma_f32_16x16x32_bf16(a10, b0, acc[1][j], 0, 0, 0);
      short8x b1v = *(const short8x*)(B0 + j * 2048 + sw1);
      acc[0][j] = __builtin_amdgcn_mfma_f32_16x16x32_bf16(a01, b1v, acc[0][j], 0, 0, 0);
      acc[1][j] = __builtin_amdgcn_mfma_f32_16x16x32_bf16(a11, b1v, acc[1][j], 0, 0, 0);
    }
  }
  int col0 = ct * BN;
  int rbase = q * 4;
#pragma unroll
  for (int i = 0; i < 2; ++i) {
#pragma unroll
    for (int j = 0; j < 8; ++j) {
      int col = col0 + j * 16 + l15;
      float bias = b2[e * D_MODEL + col];
#pragma unroll
      for (int r = 0; r < 4; ++r) {
        int grow = rt * BM + w * 32 + i * 16 + rbase + r;
        float v = acc[i][j][r] + bias;
        out2[(size_t)(e * CAP + grow) * D_MODEL + col] = f2bf(v);
      }
    }
  }
}

// ---------------- Combine ----------------
__global__ __launch_bounds__(256) void combine_kernel(
    const int* __restrict__ token_rows, const float2* __restrict__ tok_gates,
    const short* __restrict__ out2, float* __restrict__ y) {
  int t = blockIdx.x;
  int r0 = token_rows[2 * t], r1 = token_rows[2 * t + 1];
  float2 g = tok_gates[t];
  int d = threadIdx.x * 4;
  float4 v; v.x = v.y = v.z = v.w = 0.f;
  if (r0 >= 0) {
    short4x a = *(const short4x*)(out2 + (size_t)r0 * D_MODEL + d);
    v.x += g.x * bf2f(a[0]); v.y += g.x * bf2f(a[1]);
    v.z += g.x * bf2f(a[2]); v.w += g.x * bf2f(a[3]);
  }
  if (r1 >= 0) {
    short4x a = *(const short4x*)(out2 + (size_t)r1 * D_MODEL + d);
    v.x += g.y * bf2f(a[0]); v.y += g.y * bf2f(a[1]);
    v.z += g.y * bf2f(a[2]); v.w += g.y * bf2f(a[3]);
  }
  *(float4*)(y + (size_t)t * D_MODEL + d) = v;
}

extern "C" void kernel_launch(void* const* d_in, const int* in_sizes, int n_in,
                              void* d_out, int out_size, void* d_ws, size_t ws_size,
                              hipStream_t stream) {
  const float* x  = (const float*)d_in[0];
  const float* rw = (const float*)d_in[1];
  const float* rb = (const float*)d_in[2];
  const float* w1 = (const float*)d_in[3];
  const float* b1 = (const float*)d_in[4];
  const float* w2 = (const float*)d_in[5];
  const float* b2 = (const float*)d_in[6];
  float* y = (float*)d_out;
  (void)in_sizes; (void)n_in; (void)out_size; (void)ws_size;

  char* p = (char*)d_ws;
  size_t off = 0;
  auto take = [&](size_t bytes) -> void* {
    void* r = p + off;
    off = (off + bytes + 255) & ~(size_t)255;
    return r;
  };
  int2*   tok_experts = (int2*)  take((size_t)NTOK * sizeof(int2));
  float2* tok_gates   = (float2*)take((size_t)NTOK * sizeof(float2));
  int*    slot_token  = (int*)   take((size_t)NEXP * CAP * sizeof(int));
  int*    token_rows  = (int*)   take((size_t)NTOK * 2 * sizeof(int));
  short*  xbf         = (short*) take((size_t)NTOK * D_MODEL * sizeof(short));
  short*  w1t         = (short*) take((size_t)NEXP * D_HIDDEN * D_MODEL * sizeof(short));
  short*  w2t         = (short*) take((size_t)NEXP * D_MODEL * D_HIDDEN * sizeof(short));
  short*  h           = (short*) take((size_t)NEXP * CAP * D_HIDDEN * sizeof(short));
  short*  out2        = (short*) take((size_t)NEXP * CAP * D_MODEL * sizeof(short));

  router_kernel<<<NTOK / 4, 256, 0, stream>>>(x, rw, rb, tok_experts, tok_gates);
  scan_kernel<<<NEXP, 1024, 0, stream>>>(tok_experts, slot_token, token_rows);
  convert_x_kernel<<<NTOK * D_MODEL / (256 * 8), 256, 0, stream>>>(x, xbf);
  transpose_kernel<<<dim3(D_HIDDEN / 64, D_MODEL / 64, NEXP), 256, 0, stream>>>(
      w1, w1t, D_MODEL, D_HIDDEN);
  transpose_kernel<<<dim3(D_MODEL / 64, D_HIDDEN / 64, NEXP), 256, 0, stream>>>(
      w2, w2t, D_HIDDEN, D_MODEL);
  gemm1_fast<<<dim3(D_HIDDEN / BN, CAP / BM, NEXP), 256, 0, stream>>>(
      xbf, w1t, b1, slot_token, h);
  gemm2_fast<<<dim3(D_MODEL / BN, CAP / BM, NEXP), 256, 0, stream>>>(
      h, w2t, b2, out2);
  combine_kernel<<<NTOK, 256, 0, stream>>>(token_rows, tok_gates, out2, y);
}

// Round 5
// 619.889 us; speedup vs baseline: 1.1231x; 1.1231x over previous
//
#include <hip/hip_runtime.h>
#include <math.h>

#define D_MODEL 1024
#define D_HIDDEN 4096
#define NEXP 8
#define NTOK 8192
#define CAP 1280

#define BM 128
#define BN 128
#define BK 32
#define KSPLIT 2
#define KHALF (D_HIDDEN / KSPLIT)

typedef __attribute__((ext_vector_type(8))) short short8x;
typedef __attribute__((ext_vector_type(4))) short short4x;
typedef __attribute__((ext_vector_type(4))) float float4x;

__device__ __forceinline__ short f2bf(float f) {
  unsigned u = __float_as_uint(f);
  unsigned r = (u + 0x7FFFu + ((u >> 16) & 1u)) >> 16;  // RNE
  return (short)r;
}
__device__ __forceinline__ float bf2f(short s) {
  return __uint_as_float(((unsigned)(unsigned short)s) << 16);
}
// tanh-GELU via sigmoid; abs err ~5e-4, far under threshold headroom. ~8 VALU.
__device__ __forceinline__ float gelu_fast(float v) {
  float u2 = v * (1.5957691216f + 0.0713548163f * v * v);
  return v / (1.0f + __expf(-u2));
}

#define GLDS16(g, l)                                                        \
  __builtin_amdgcn_global_load_lds(                                         \
      (const __attribute__((address_space(1))) void*)(g),                   \
      (__attribute__((address_space(3))) void*)(l), 16, 0, 0)

// ---------------- convert x: fp32 -> bf16, same layout ----------------
__global__ __launch_bounds__(256) void convert_x_kernel(
    const float* __restrict__ x, short* __restrict__ xbf) {
  size_t i = ((size_t)blockIdx.x * 256 + threadIdx.x) * 8;
  const float4* s = (const float4*)(x + i);
  float4 a = s[0], b = s[1];
  short8x o;
  o[0] = f2bf(a.x); o[1] = f2bf(a.y); o[2] = f2bf(a.z); o[3] = f2bf(a.w);
  o[4] = f2bf(b.x); o[5] = f2bf(b.y); o[6] = f2bf(b.z); o[7] = f2bf(b.w);
  *(short8x*)(xbf + i) = o;
}

// ------- transpose+convert: in [E][K][N] fp32 -> out [E][N][K] bf16 -------
// shfl-paired bf16 packing -> dword LDS tile [kpair][n] (pad 65),
// b32 LDS ops (<=2-way banks), 32 B coalesced global stores.
__global__ __launch_bounds__(256) void transpose_kernel(
    const float* __restrict__ in, short* __restrict__ out, int K, int N) {
  __shared__ unsigned tile[32 * 65];
  int n0 = blockIdx.x * 64, k0 = blockIdx.y * 64, e = blockIdx.z;
  int t = threadIdx.x;
  int rr = t >> 4;        // 0..15 (row within 16-row pass)
  int cc = (t & 15) * 4;  // n within tile
  const float* src = in + (size_t)e * K * N + (size_t)(k0 + rr) * N + n0 + cc;
  bool packer = (rr & 1) == 0;
  int mb = rr >> 1;
#pragma unroll
  for (int p = 0; p < 4; ++p) {
    float4 v = *(const float4*)(src + (size_t)p * 16 * N);
    float4 wv;
    wv.x = __shfl_xor(v.x, 16, 64);  // partner row r+1 (rr odd lane)
    wv.y = __shfl_xor(v.y, 16, 64);
    wv.z = __shfl_xor(v.z, 16, 64);
    wv.w = __shfl_xor(v.w, 16, 64);
    if (packer) {
      int m = p * 8 + mb;  // local kpair 0..31
      unsigned* tr = &tile[m * 65 + cc];
      tr[0] = (unsigned)(unsigned short)f2bf(v.x) |
              ((unsigned)(unsigned short)f2bf(wv.x) << 16);
      tr[1] = (unsigned)(unsigned short)f2bf(v.y) |
              ((unsigned)(unsigned short)f2bf(wv.y) << 16);
      tr[2] = (unsigned)(unsigned short)f2bf(v.z) |
              ((unsigned)(unsigned short)f2bf(wv.z) << 16);
      tr[3] = (unsigned)(unsigned short)f2bf(v.w) |
              ((unsigned)(unsigned short)f2bf(wv.w) << 16);
    }
  }
  __syncthreads();
  int n = t >> 2, q = t & 3;
  const unsigned* col = &tile[q * 8 * 65 + n];
  unsigned d[8];
#pragma unroll
  for (int j = 0; j < 8; ++j) d[j] = col[j * 65];
  short* dst = out + (size_t)e * N * K + (size_t)(n0 + n) * K + k0 + q * 16;
  ((uint4*)dst)[0] = make_uint4(d[0], d[1], d[2], d[3]);
  ((uint4*)dst)[1] = make_uint4(d[4], d[5], d[6], d[7]);
}

// ---------------- Router ----------------
__global__ __launch_bounds__(256) void router_kernel(
    const float* __restrict__ x, const float* __restrict__ rw,
    const float* __restrict__ rb, int2* __restrict__ tok_experts,
    float2* __restrict__ tok_gates) {
  int t = blockIdx.x * 4 + (threadIdx.x >> 6);
  int lane = threadIdx.x & 63;
  const float* xr = x + (size_t)t * D_MODEL;
  float acc[8];
#pragma unroll
  for (int e = 0; e < 8; ++e) acc[e] = 0.f;
#pragma unroll
  for (int kk = 0; kk < 16; ++kk) {
    int k = kk * 64 + lane;
    float xv = xr[k];
    const float4* wr = (const float4*)(rw + (size_t)k * 8);
    float4 w0 = wr[0], w1v = wr[1];
    acc[0] += xv * w0.x;  acc[1] += xv * w0.y;
    acc[2] += xv * w0.z;  acc[3] += xv * w0.w;
    acc[4] += xv * w1v.x; acc[5] += xv * w1v.y;
    acc[6] += xv * w1v.z; acc[7] += xv * w1v.w;
  }
#pragma unroll
  for (int off = 32; off > 0; off >>= 1) {
#pragma unroll
    for (int e = 0; e < 8; ++e) acc[e] += __shfl_xor(acc[e], off, 64);
  }
  if (lane == 0) {
    float lg[8];
#pragma unroll
    for (int e = 0; e < 8; ++e) lg[e] = acc[e] + rb[e];
    int e0 = 0;
#pragma unroll
    for (int e = 1; e < 8; ++e) if (lg[e] > lg[e0]) e0 = e;
    int e1 = (e0 == 0) ? 1 : 0;
#pragma unroll
    for (int e = 0; e < 8; ++e) if (e != e0 && lg[e] > lg[e1]) e1 = e;
    float mx = lg[e0];
    float s = 0.f;
#pragma unroll
    for (int e = 0; e < 8; ++e) s += expf(lg[e] - mx);
    float inv = 1.f / s;
    tok_experts[t] = make_int2(e0, e1);
    tok_gates[t] = make_float2(expf(lg[e0] - mx) * inv, expf(lg[e1] - mx) * inv);
  }
}

// ---------------- Scan ----------------
__global__ __launch_bounds__(1024) void scan_kernel(
    const int2* __restrict__ tok_experts, int* __restrict__ slot_token,
    int* __restrict__ token_rows) {
  int e = blockIdx.x;
  int tid = threadIdx.x;
  for (int i = tid; i < CAP; i += 1024) slot_token[e * CAP + i] = -1;
  __shared__ int wsum[16];
  __shared__ int running;
  if (tid == 0) running = 0;
  __syncthreads();
  int lane = tid & 63, wid = tid >> 6;
  unsigned long long lmask = (1ull << lane) - 1ull;
  for (int base = 0; base < NTOK; base += 1024) {
    int t = base + tid;
    int2 ee = tok_experts[t];
    int m = (ee.x == e || ee.y == e) ? 1 : 0;
    unsigned long long bal = __ballot(m);
    int prefix = __popcll(bal & lmask);
    if (lane == 0) wsum[wid] = (int)__popcll(bal);
    __syncthreads();
    if (tid == 0) {
      int s = running;
#pragma unroll
      for (int w = 0; w < 16; ++w) { int v = wsum[w]; wsum[w] = s; s += v; }
      running = s;
    }
    __syncthreads();
    if (m) {
      int pos = wsum[wid] + prefix;
      int which = (ee.x == e) ? 0 : 1;
      if (pos < CAP) {
        slot_token[e * CAP + pos] = t;
        token_rows[2 * t + which] = e * CAP + pos;
      } else {
        token_rows[2 * t + which] = -1;
      }
    }
    __syncthreads();
  }
}

// LDS tile (r3-proven, 0 conflicts): 128 rows x 64 B, unpadded; 16B-chunk c of
// row r at unit r*4 + ((c + (r>>1)) & 3).

// ---------------- GEMM1: h = gelu(gather(xbf) @ w1t[e]^T + b1[e]) ------------
// flat grid 2560: e = bx&7 (XCD), ct = (bx>>3)&31, rt = bx>>8
__global__ __launch_bounds__(256) void gemm1_fast(
    const short* __restrict__ xbf, const short* __restrict__ w1t,
    const float* __restrict__ b1, const int* __restrict__ slot_token,
    short* __restrict__ h) {
  __shared__ short As[BM * BK];
  __shared__ short Bs[BN * BK];
  __shared__ int rowtok[BM];
  int bx = blockIdx.x;
  int e = bx & 7, ct = (bx >> 3) & 31, rt = bx >> 8;
  int tid = threadIdx.x;
  if (tid < BM) {
    int t = slot_token[e * CAP + rt * BM + tid];
    rowtok[tid] = t < 0 ? 0 : t;  // dropped slots: garbage rows, never gathered
  }
  __syncthreads();
  int lane = tid & 63, w = tid >> 6;

  const char* agm[2]; const char* bgm[2];
  char* alds[2]; char* blds[2];
#pragma unroll
  for (int p = 0; p < 2; ++p) {
    int r = w * 32 + p * 16 + (lane >> 2);
    int c = ((lane & 3) - ((r >> 1) & 3)) & 3;
    agm[p] = (const char*)(xbf + (size_t)rowtok[r] * D_MODEL + c * 8);
    alds[p] = (char*)As + (w * 32 + p * 16) * 64 + lane * 16;
    bgm[p] = (const char*)(w1t + ((size_t)e * D_HIDDEN + ct * BN + r) * D_MODEL + c * 8);
    blds[p] = (char*)Bs + (w * 32 + p * 16) * 64 + lane * 16;
  }
  int l15 = lane & 15, q = lane >> 4;
  int swz = (q + ((l15 >> 1) & 3)) & 3;
  const char* afb = (const char*)As + (w * 32 + l15) * 64 + swz * 16;
  const char* bfb = (const char*)Bs + l15 * 64 + swz * 16;

  float4x acc[2][8];
#pragma unroll
  for (int i = 0; i < 2; ++i)
#pragma unroll
    for (int j = 0; j < 8; ++j) acc[i][j] = (float4x){0.f, 0.f, 0.f, 0.f};

  for (int k0 = 0; k0 < D_MODEL; k0 += BK) {
    __syncthreads();
    int kb = k0 * 2;
    GLDS16(agm[0] + kb, alds[0]);
    GLDS16(agm[1] + kb, alds[1]);
    GLDS16(bgm[0] + kb, blds[0]);
    GLDS16(bgm[1] + kb, blds[1]);
    __syncthreads();
    short8x a0 = *(const short8x*)afb;
    short8x a1 = *(const short8x*)(afb + 1024);
#pragma unroll
    for (int j = 0; j < 8; ++j) {
      short8x b = *(const short8x*)(bfb + j * 1024);
      acc[0][j] = __builtin_amdgcn_mfma_f32_16x16x32_bf16(a0, b, acc[0][j], 0, 0, 0);
      acc[1][j] = __builtin_amdgcn_mfma_f32_16x16x32_bf16(a1, b, acc[1][j], 0, 0, 0);
    }
  }
  int col0 = ct * BN;
  int rbase = q * 4;
#pragma unroll
  for (int i = 0; i < 2; ++i) {
#pragma unroll
    for (int j = 0; j < 8; ++j) {
      int col = col0 + j * 16 + l15;
      float bias = b1[e * D_HIDDEN + col];
#pragma unroll
      for (int r = 0; r < 4; ++r) {
        int grow = rt * BM + w * 32 + i * 16 + rbase + r;
        float v = gelu_fast(acc[i][j][r] + bias);
        h[(size_t)(e * CAP + grow) * D_HIDDEN + col] = f2bf(v);
      }
    }
  }
}

// ---------------- GEMM2 (2-way K-split): partial = h @ w2t[e]^T (+b2 if ks=0) -
// flat grid 1280: e = bx&7 (XCD), ct = (bx>>3)&7, rt = bx>>7 ... see mapping
__global__ __launch_bounds__(256) void gemm2_fast(
    const short* __restrict__ h, const short* __restrict__ w2t,
    const float* __restrict__ b2, short* __restrict__ p0,
    short* __restrict__ p1) {
  __shared__ short As[BM * BK];
  __shared__ short Bs[BN * BK];
  int bx = blockIdx.x;
  int e = bx & 7;
  int rest = bx >> 3;        // 0..159
  int ct = rest & 7;         // 8 ct
  int rg = rest >> 3;        // 0..19
  int rt = rg >> 1, ks = rg & 1;
  int koff = ks * KHALF;
  int tid = threadIdx.x;
  int lane = tid & 63, w = tid >> 6;

  const char* agm[2]; const char* bgm[2];
  char* alds[2]; char* blds[2];
#pragma unroll
  for (int p = 0; p < 2; ++p) {
    int r = w * 32 + p * 16 + (lane >> 2);
    int c = ((lane & 3) - ((r >> 1) & 3)) & 3;
    agm[p] = (const char*)(h + (size_t)(e * CAP + rt * BM + r) * D_HIDDEN + koff + c * 8);
    alds[p] = (char*)As + (w * 32 + p * 16) * 64 + lane * 16;
    bgm[p] = (const char*)(w2t + ((size_t)e * D_MODEL + ct * BN + r) * D_HIDDEN + koff + c * 8);
    blds[p] = (char*)Bs + (w * 32 + p * 16) * 64 + lane * 16;
  }
  int l15 = lane & 15, q = lane >> 4;
  int swz = (q + ((l15 >> 1) & 3)) & 3;
  const char* afb = (const char*)As + (w * 32 + l15) * 64 + swz * 16;
  const char* bfb = (const char*)Bs + l15 * 64 + swz * 16;

  float4x acc[2][8];
#pragma unroll
  for (int i = 0; i < 2; ++i)
#pragma unroll
    for (int j = 0; j < 8; ++j) acc[i][j] = (float4x){0.f, 0.f, 0.f, 0.f};

  for (int k0 = 0; k0 < KHALF; k0 += BK) {
    __syncthreads();
    int kb = k0 * 2;
    GLDS16(agm[0] + kb, alds[0]);
    GLDS16(agm[1] + kb, alds[1]);
    GLDS16(bgm[0] + kb, blds[0]);
    GLDS16(bgm[1] + kb, blds[1]);
    __syncthreads();
    short8x a0 = *(const short8x*)afb;
    short8x a1 = *(const short8x*)(afb + 1024);
#pragma unroll
    for (int j = 0; j < 8; ++j) {
      short8x b = *(const short8x*)(bfb + j * 1024);
      acc[0][j] = __builtin_amdgcn_mfma_f32_16x16x32_bf16(a0, b, acc[0][j], 0, 0, 0);
      acc[1][j] = __builtin_amdgcn_mfma_f32_16x16x32_bf16(a1, b, acc[1][j], 0, 0, 0);
    }
  }
  short* dst = ks == 0 ? p0 : p1;
  int col0 = ct * BN;
  int rbase = q * 4;
#pragma unroll
  for (int i = 0; i < 2; ++i) {
#pragma unroll
    for (int j = 0; j < 8; ++j) {
      int col = col0 + j * 16 + l15;
      float bias = (ks == 0) ? b2[e * D_MODEL + col] : 0.f;
#pragma unroll
      for (int r = 0; r < 4; ++r) {
        int grow = rt * BM + w * 32 + i * 16 + rbase + r;
        float v = acc[i][j][r] + bias;
        dst[(size_t)(e * CAP + grow) * D_MODEL + col] = f2bf(v);
      }
    }
  }
}

// ---------------- Combine: y[t] = sum_i g_i*(p0[r_i]+p1[r_i]) ----------------
__global__ __launch_bounds__(256) void combine_kernel(
    const int* __restrict__ token_rows, const float2* __restrict__ tok_gates,
    const short* __restrict__ p0, const short* __restrict__ p1,
    float* __restrict__ y) {
  int t = blockIdx.x;
  int r0 = token_rows[2 * t], r1 = token_rows[2 * t + 1];
  float2 g = tok_gates[t];
  int d = threadIdx.x * 4;
  float4 v; v.x = v.y = v.z = v.w = 0.f;
  if (r0 >= 0) {
    short4x a = *(const short4x*)(p0 + (size_t)r0 * D_MODEL + d);
    short4x b = *(const short4x*)(p1 + (size_t)r0 * D_MODEL + d);
    v.x += g.x * (bf2f(a[0]) + bf2f(b[0]));
    v.y += g.x * (bf2f(a[1]) + bf2f(b[1]));
    v.z += g.x * (bf2f(a[2]) + bf2f(b[2]));
    v.w += g.x * (bf2f(a[3]) + bf2f(b[3]));
  }
  if (r1 >= 0) {
    short4x a = *(const short4x*)(p0 + (size_t)r1 * D_MODEL + d);
    short4x b = *(const short4x*)(p1 + (size_t)r1 * D_MODEL + d);
    v.x += g.y * (bf2f(a[0]) + bf2f(b[0]));
    v.y += g.y * (bf2f(a[1]) + bf2f(b[1]));
    v.z += g.y * (bf2f(a[2]) + bf2f(b[2]));
    v.w += g.y * (bf2f(a[3]) + bf2f(b[3]));
  }
  *(float4*)(y + (size_t)t * D_MODEL + d) = v;
}

extern "C" void kernel_launch(void* const* d_in, const int* in_sizes, int n_in,
                              void* d_out, int out_size, void* d_ws, size_t ws_size,
                              hipStream_t stream) {
  const float* x  = (const float*)d_in[0];
  const float* rw = (const float*)d_in[1];
  const float* rb = (const float*)d_in[2];
  const float* w1 = (const float*)d_in[3];
  const float* b1 = (const float*)d_in[4];
  const float* w2 = (const float*)d_in[5];
  const float* b2 = (const float*)d_in[6];
  float* y = (float*)d_out;
  (void)in_sizes; (void)n_in; (void)out_size; (void)ws_size;

  char* p = (char*)d_ws;
  size_t off = 0;
  auto take = [&](size_t bytes) -> void* {
    void* r = p + off;
    off = (off + bytes + 255) & ~(size_t)255;
    return r;
  };
  // identical carve to round-3/4 (proven to fit ws_size)
  int2*   tok_experts = (int2*)  take((size_t)NTOK * sizeof(int2));
  float2* tok_gates   = (float2*)take((size_t)NTOK * sizeof(float2));
  int*    slot_token  = (int*)   take((size_t)NEXP * CAP * sizeof(int));
  int*    token_rows  = (int*)   take((size_t)NTOK * 2 * sizeof(int));
  short*  xbf         = (short*) take((size_t)NTOK * D_MODEL * sizeof(short));
  short*  w1t         = (short*) take((size_t)NEXP * D_HIDDEN * D_MODEL * sizeof(short));
  short*  w2t         = (short*) take((size_t)NEXP * D_MODEL * D_HIDDEN * sizeof(short));
  short*  h           = (short*) take((size_t)NEXP * CAP * D_HIDDEN * sizeof(short));
  short*  out2        = (short*) take((size_t)NEXP * CAP * D_MODEL * sizeof(short));
  // K-split partial 1 overlays w1t (dead after gemm1; 21 MB <= 64 MB)
  short* part0 = out2;
  short* part1 = w1t;

  router_kernel<<<NTOK / 4, 256, 0, stream>>>(x, rw, rb, tok_experts, tok_gates);
  scan_kernel<<<NEXP, 1024, 0, stream>>>(tok_experts, slot_token, token_rows);
  convert_x_kernel<<<NTOK * D_MODEL / (256 * 8), 256, 0, stream>>>(x, xbf);
  transpose_kernel<<<dim3(D_HIDDEN / 64, D_MODEL / 64, NEXP), 256, 0, stream>>>(
      w1, w1t, D_MODEL, D_HIDDEN);
  transpose_kernel<<<dim3(D_MODEL / 64, D_HIDDEN / 64, NEXP), 256, 0, stream>>>(
      w2, w2t, D_HIDDEN, D_MODEL);
  gemm1_fast<<<2560, 256, 0, stream>>>(xbf, w1t, b1, slot_token, h);
  gemm2_fast<<<1280, 256, 0, stream>>>(h, w2t, b2, part0, part1);
  combine_kernel<<<NTOK, 256, 0, stream>>>(token_rows, tok_gates, part0, part1, y);
}